// Round 9
// baseline (25.007 us; speedup 1.0000x reference)
//
#include <hip/hip_runtime.h>

#define TPL_SIZE 16384
#define TPL_K 16
#define TPL_ND 5
#define TPL_BLK 512
#define TPL_PTS 4                                  // points per thread
#define TPL_SPAN (TPL_BLK * TPL_PTS)               // 2048 points per block
#define TPL_BPB (TPL_SIZE / TPL_SPAN)              // 8 blocks per batch
#define TPL_NXCD 8

// 256 blocks x 512 threads; each block stages its ENTIRE batch table
// (16384 x {px_u16|py_u16<<16, v_f32} = 128 KB) into LDS, then each thread
// solves FOUR points with a DEPTH-2 software pipeline on edge/dist loads
// (64 B/thread in flight under both the staging loop and the compute).
// XCD remap (R8, kept): a batch's 8 blocks share blockIdx%8 -> same XCD L2,
// table fetched from HBM ~once per batch. 512-thread blocks: 1024-thread
// variants spilled (64-VGPR ceiling, R5/R6).
__global__ __launch_bounds__(TPL_BLK, 2) void tp_lds_kernel(
    const float* __restrict__ x,
    const float* __restrict__ points,
    const int*   __restrict__ edge_index,
    const float* __restrict__ dtp,
    const float* __restrict__ dist,
    const float* __restrict__ weight,
    float* __restrict__ out)
{
    extern __shared__ uint32_t lds_raw[];
    uint2* lds_pv = reinterpret_cast<uint2*>(lds_raw);   // [TPL_SIZE] = 128 KB

    const int tid = threadIdx.x;
    const int blk = blockIdx.x;

    // blk -> (batch, chunk): xcd = blk&7 ; 4 batches per XCD
    const int xcd   = blk & (TPL_NXCD - 1);
    const int batch = xcd * 4 + (blk >> 6);          // [0,32)
    const int chunk = (blk >> 3) & (TPL_BPB - 1);    // [0,8)

    const size_t base = (size_t)batch * TPL_SIZE + chunk * TPL_SPAN;

    // ---- depth-2 prefetch: issue point 0 AND point 1 streaming loads FIRST
    int4   ci2[2][4];
    float4 cw2[2][4];
    #pragma unroll
    for (int d = 0; d < 2; ++d) {
        const size_t rw = base + d * TPL_BLK + tid;
        const int4*   ei = reinterpret_cast<const int4*>(edge_index + rw * TPL_K);
        const float4* dw = reinterpret_cast<const float4*>(dist      + rw * TPL_K);
        #pragma unroll
        for (int q = 0; q < 4; ++q) { ci2[d][q] = ei[q]; cw2[d][q] = dw[q]; }
    }

    // ---- stage + quantize the whole batch table into LDS ----
    // vectorized: 4 entries/thread/iter (2x float4 points + 1x float4 x,
    // 2x uint4 LDS writes) -> 8 iterations instead of 32
    {
        const float4* pb4 = reinterpret_cast<const float4*>(points + (size_t)batch * TPL_SIZE * 2);
        const float4* xb4 = reinterpret_cast<const float4*>(x + (size_t)batch * TPL_SIZE);
        uint4* lds4 = reinterpret_cast<uint4*>(lds_raw);
        #pragma unroll
        for (int k = 0; k < TPL_SIZE / (TPL_BLK * 4); ++k) {
            int e4 = k * TPL_BLK + tid;          // group of 4 entries
            float4 pA = pb4[e4 * 2];             // points for entries 0,1
            float4 pB = pb4[e4 * 2 + 1];         // points for entries 2,3
            float4 xv = xb4[e4];                 // values for entries 0..3
            float pxs[4] = {pA.x, pA.z, pB.x, pB.z};
            float pys[4] = {pA.y, pA.w, pB.y, pB.w};
            float vs[4]  = {xv.x, xv.y, xv.z, xv.w};
            unsigned packed[4];
            #pragma unroll
            for (int j = 0; j < 4; ++j) {
                unsigned ux = (unsigned)(pxs[j] * 65536.0f);
                unsigned uy = (unsigned)(pys[j] * 65536.0f);
                if (ux > 65535u) ux = 65535u;
                if (uy > 65535u) uy = 65535u;
                packed[j] = ux | (uy << 16);
            }
            uint4 w0, w1;
            w0.x = packed[0]; w0.y = __float_as_uint(vs[0]);
            w0.z = packed[1]; w0.w = __float_as_uint(vs[1]);
            w1.x = packed[2]; w1.y = __float_as_uint(vs[2]);
            w1.z = packed[3]; w1.w = __float_as_uint(vs[3]);
            lds4[e4 * 2]     = w0;
            lds4[e4 * 2 + 1] = w1;
        }
    }
    __syncthreads();

    const float wt0 = weight[0], wt1 = weight[1], wt2 = weight[2],
                wt3 = weight[3], wt4 = weight[4];
    const float dtv = dtp[0];

    #pragma unroll
    for (int p = 0; p < TPL_PTS; ++p) {
        // copy current set to locals (static indices; p&1 folds after unroll)
        int ids[TPL_K];
        float wgt[TPL_K];
        #pragma unroll
        for (int q = 0; q < 4; ++q) {
            ids[q * 4 + 0] = ci2[p & 1][q].x;
            ids[q * 4 + 1] = ci2[p & 1][q].y;
            ids[q * 4 + 2] = ci2[p & 1][q].z;
            ids[q * 4 + 3] = ci2[p & 1][q].w;
            wgt[q * 4 + 0] = cw2[p & 1][q].x;
            wgt[q * 4 + 1] = cw2[p & 1][q].y;
            wgt[q * 4 + 2] = cw2[p & 1][q].z;
            wgt[q * 4 + 3] = cw2[p & 1][q].w;
        }

        // issue prefetch for point p+2 into the slot just freed
        if (p + 2 < TPL_PTS) {
            const size_t rw = base + (p + 2) * TPL_BLK + tid;
            const int4*   ei = reinterpret_cast<const int4*>(edge_index + rw * TPL_K);
            const float4* dw = reinterpret_cast<const float4*>(dist      + rw * TPL_K);
            #pragma unroll
            for (int q = 0; q < 4; ++q) { ci2[p & 1][q] = ei[q]; cw2[p & 1][q] = dw[q]; }
        }

        const int    s   = chunk * TPL_SPAN + p * TPL_BLK + tid;
        const size_t row = base + p * TPL_BLK + tid;

        // self point from LDS (same quantization as neighbors)
        uint2 se = lds_pv[s];
        unsigned sx = se.x & 0xffffu;
        unsigned sy = se.x >> 16;
        float    sv = __uint_as_float(se.y);

        uint2 nb[TPL_K];
        #pragma unroll
        for (int t = 0; t < TPL_K; ++t) nb[t] = lds_pv[ids[t] & (TPL_SIZE - 1)];

        float ata[15], atb[TPL_ND];
        #pragma unroll
        for (int i = 0; i < 15; ++i) ata[i] = 0.0f;
        #pragma unroll
        for (int i = 0; i < TPL_ND; ++i) atb[i] = 0.0f;

        #pragma unroll
        for (int t = 0; t < TPL_K; ++t) {
            float w = wgt[t];
            int dxi = (int)(nb[t].x & 0xffffu) - (int)sx;
            int dyi = (int)(nb[t].x >> 16)     - (int)sy;
            float dx = (float)dxi * 0x1p-16f;
            float dy = (float)dyi * 0x1p-16f;
            float nv = __uint_as_float(nb[t].y);
            float a[TPL_ND];
            a[0] = dx * w;
            a[1] = dy * w;
            a[2] = 0.5f * dx * dx * w;
            a[3] = dx * dy * w;
            a[4] = 0.5f * dy * dy * w;
            float bwv = (nv - sv) * w;
            int c = 0;
            #pragma unroll
            for (int i = 0; i < TPL_ND; ++i) {
                #pragma unroll
                for (int j = i; j < TPL_ND; ++j) ata[c++] += a[i] * a[j];
                atb[i] += a[i] * bwv;
            }
        }

        // 5x5 SPD solve, fully unrolled Gaussian elimination (regs only)
        float M[TPL_ND][TPL_ND], r[TPL_ND];
        {
            int c = 0;
            #pragma unroll
            for (int i = 0; i < TPL_ND; ++i) {
                #pragma unroll
                for (int j = i; j < TPL_ND; ++j) { M[i][j] = ata[c]; M[j][i] = ata[c]; ++c; }
                r[i] = atb[i];
                M[i][i] += 1e-6f;
            }
        }
        #pragma unroll
        for (int i = 0; i < TPL_ND; ++i) {
            float inv = 1.0f / M[i][i];
            #pragma unroll
            for (int j = i + 1; j < TPL_ND; ++j) {
                float f = M[j][i] * inv;
                #pragma unroll
                for (int cc = i + 1; cc < TPL_ND; ++cc) M[j][cc] -= f * M[i][cc];
                r[j] -= f * r[i];
            }
        }
        float sol[TPL_ND];
        #pragma unroll
        for (int i = TPL_ND - 1; i >= 0; --i) {
            float sv2 = r[i];
            #pragma unroll
            for (int cc = i + 1; cc < TPL_ND; ++cc) sv2 -= M[i][cc] * sol[cc];
            sol[i] = sv2 / M[i][i];
        }

        float du = sol[0] * wt0 + sol[1] * wt1 + sol[2] * wt2
                 + sol[3] * wt3 + sol[4] * wt4;
        out[row] = sv + dtv * du;
    }
}

extern "C" void kernel_launch(void* const* d_in, const int* in_sizes, int n_in,
                              void* d_out, int out_size, void* d_ws, size_t ws_size,
                              hipStream_t stream) {
    const float* x          = (const float*)d_in[0];
    const float* points     = (const float*)d_in[1];
    const int*   edge_index = (const int*)d_in[2];
    const float* dtp        = (const float*)d_in[3];
    const float* dist       = (const float*)d_in[4];
    const float* weight     = (const float*)d_in[5];
    float* out = (float*)d_out;

    int total = out_size;                    // B * SIZE = 524288
    int grid  = total / TPL_SPAN;            // 256 blocks (8 per batch)
    size_t lds_bytes = (size_t)TPL_SIZE * sizeof(uint2);  // 128 KB

    tp_lds_kernel<<<grid, TPL_BLK, lds_bytes, stream>>>(
        x, points, edge_index, dtp, dist, weight, out);
}

// Round 10
// 21.144 us; speedup vs baseline: 1.1827x; 1.1827x over previous
//
#include <hip/hip_runtime.h>

#define TPL_SIZE 16384
#define TPL_K 16
#define TPL_ND 5
#define TPL_BLK 512
#define TPL_PTS 4                                  // points per thread
#define TPL_SPAN (TPL_BLK * TPL_PTS)               // 2048 points per block
#define TPL_BPB (TPL_SIZE / TPL_SPAN)              // 8 blocks per batch
#define TPL_ITER (TPL_SIZE / TPL_BLK)              // 32 staging iterations
#define TPL_NXCD 8

// R8 structure (23.4 us known-good) + fast reciprocal solve.
// - 256 blocks x 512 threads; block stages the ENTIRE batch table
//   (16384 x {px_u16|py_u16<<16, v_f32} = 128 KB) into LDS; each thread
//   solves FOUR points with a depth-1 prefetch pipeline on edge/dist.
// - XCD remap: a batch's 8 blocks share blockIdx%8 -> same XCD L2; the
//   192 KB table is fetched from HBM ~once per batch (R8: -4 us).
// - 512-thread blocks: 1024-thread variants hit a 64-VGPR compiler ceiling
//   and spilled 60-90 MB to scratch (R5/R6).
// - NEW (R10): v_rcp_f32 instead of IEEE division in the 5x5 solve, and the
//   pivot reciprocals are reused in back-substitution (5 rcp, 0 divides,
//   ~80 fewer VALU ops/point; rcp rel err ~2^-22, noise vs 0.099 tolerance).
__global__ __launch_bounds__(TPL_BLK, 2) void tp_lds_kernel(
    const float* __restrict__ x,
    const float* __restrict__ points,
    const int*   __restrict__ edge_index,
    const float* __restrict__ dtp,
    const float* __restrict__ dist,
    const float* __restrict__ weight,
    float* __restrict__ out)
{
    extern __shared__ uint2 lds_pv[];   // [TPL_SIZE] = 128 KB

    const int tid = threadIdx.x;
    const int blk = blockIdx.x;

    // blk -> (batch, chunk): xcd = blk&7 ; 4 batches per XCD
    const int xcd   = blk & (TPL_NXCD - 1);
    const int batch = xcd * 4 + (blk >> 6);          // [0,32)
    const int chunk = (blk >> 3) & (TPL_BPB - 1);    // [0,8)

    const size_t base = (size_t)batch * TPL_SIZE + chunk * TPL_SPAN;

    // ---- issue point 0's streaming loads FIRST (latency hides under staging)
    int4   ci[4];
    float4 cw[4];
    {
        const int4*   ei = reinterpret_cast<const int4*>(edge_index + (base + tid) * TPL_K);
        const float4* dw = reinterpret_cast<const float4*>(dist      + (base + tid) * TPL_K);
        ci[0] = ei[0]; ci[1] = ei[1]; ci[2] = ei[2]; ci[3] = ei[3];
        cw[0] = dw[0]; cw[1] = dw[1]; cw[2] = dw[2]; cw[3] = dw[3];
    }

    // ---- stage + quantize the whole batch table into LDS (coalesced) ----
    const float2* pb = reinterpret_cast<const float2*>(points) + (size_t)batch * TPL_SIZE;
    const float*  xb = x + (size_t)batch * TPL_SIZE;

    #pragma unroll
    for (int k = 0; k < TPL_ITER; ++k) {
        int i = tid + k * TPL_BLK;
        float2 p = pb[i];
        float  v = xb[i];
        unsigned ux = (unsigned)(p.x * 65536.0f);
        unsigned uy = (unsigned)(p.y * 65536.0f);
        if (ux > 65535u) ux = 65535u;
        if (uy > 65535u) uy = 65535u;
        uint2 e;
        e.x = ux | (uy << 16);
        e.y = __float_as_uint(v);
        lds_pv[i] = e;
    }
    __syncthreads();

    const float wt0 = weight[0], wt1 = weight[1], wt2 = weight[2],
                wt3 = weight[3], wt4 = weight[4];
    const float dtv = dtp[0];

    #pragma unroll
    for (int p = 0; p < TPL_PTS; ++p) {
        // prefetch next point's edge/dist while computing this one
        int4   ni[4];
        float4 nw[4];
        if (p < TPL_PTS - 1) {
            const size_t rown = base + (p + 1) * TPL_BLK + tid;
            const int4*   ei = reinterpret_cast<const int4*>(edge_index + rown * TPL_K);
            const float4* dw = reinterpret_cast<const float4*>(dist      + rown * TPL_K);
            ni[0] = ei[0]; ni[1] = ei[1]; ni[2] = ei[2]; ni[3] = ei[3];
            nw[0] = dw[0]; nw[1] = dw[1]; nw[2] = dw[2]; nw[3] = dw[3];
        }

        const int    s   = chunk * TPL_SPAN + p * TPL_BLK + tid;
        const size_t row = base + p * TPL_BLK + tid;

        // self point from LDS (same quantization as neighbors)
        uint2 se = lds_pv[s];
        unsigned sx = se.x & 0xffffu;
        unsigned sy = se.x >> 16;
        float    sv = __uint_as_float(se.y);

        int ids[TPL_K] = {ci[0].x, ci[0].y, ci[0].z, ci[0].w,
                          ci[1].x, ci[1].y, ci[1].z, ci[1].w,
                          ci[2].x, ci[2].y, ci[2].z, ci[2].w,
                          ci[3].x, ci[3].y, ci[3].z, ci[3].w};
        float wgt[TPL_K] = {cw[0].x, cw[0].y, cw[0].z, cw[0].w,
                            cw[1].x, cw[1].y, cw[1].z, cw[1].w,
                            cw[2].x, cw[2].y, cw[2].z, cw[2].w,
                            cw[3].x, cw[3].y, cw[3].z, cw[3].w};

        uint2 nb[TPL_K];
        #pragma unroll
        for (int t = 0; t < TPL_K; ++t) nb[t] = lds_pv[ids[t] & (TPL_SIZE - 1)];

        float ata[15], atb[TPL_ND];
        #pragma unroll
        for (int i = 0; i < 15; ++i) ata[i] = 0.0f;
        #pragma unroll
        for (int i = 0; i < TPL_ND; ++i) atb[i] = 0.0f;

        #pragma unroll
        for (int t = 0; t < TPL_K; ++t) {
            float w = wgt[t];
            int dxi = (int)(nb[t].x & 0xffffu) - (int)sx;
            int dyi = (int)(nb[t].x >> 16)     - (int)sy;
            float dx = (float)dxi * 0x1p-16f;
            float dy = (float)dyi * 0x1p-16f;
            float nv = __uint_as_float(nb[t].y);
            float a[TPL_ND];
            a[0] = dx * w;
            a[1] = dy * w;
            a[2] = 0.5f * dx * dx * w;
            a[3] = dx * dy * w;
            a[4] = 0.5f * dy * dy * w;
            float bwv = (nv - sv) * w;
            int c = 0;
            #pragma unroll
            for (int i = 0; i < TPL_ND; ++i) {
                #pragma unroll
                for (int j = i; j < TPL_ND; ++j) ata[c++] += a[i] * a[j];
                atb[i] += a[i] * bwv;
            }
        }

        // 5x5 SPD solve, fully unrolled Gaussian elimination (regs only)
        // v_rcp_f32 pivots; reciprocals reused in back-substitution.
        float M[TPL_ND][TPL_ND], r[TPL_ND], pinv[TPL_ND];
        {
            int c = 0;
            #pragma unroll
            for (int i = 0; i < TPL_ND; ++i) {
                #pragma unroll
                for (int j = i; j < TPL_ND; ++j) { M[i][j] = ata[c]; M[j][i] = ata[c]; ++c; }
                r[i] = atb[i];
                M[i][i] += 1e-6f;
            }
        }
        #pragma unroll
        for (int i = 0; i < TPL_ND; ++i) {
            float inv = __builtin_amdgcn_rcpf(M[i][i]);
            pinv[i] = inv;
            #pragma unroll
            for (int j = i + 1; j < TPL_ND; ++j) {
                float f = M[j][i] * inv;
                #pragma unroll
                for (int cc = i + 1; cc < TPL_ND; ++cc) M[j][cc] -= f * M[i][cc];
                r[j] -= f * r[i];
            }
        }
        float sol[TPL_ND];
        #pragma unroll
        for (int i = TPL_ND - 1; i >= 0; --i) {
            float sv2 = r[i];
            #pragma unroll
            for (int cc = i + 1; cc < TPL_ND; ++cc) sv2 -= M[i][cc] * sol[cc];
            sol[i] = sv2 * pinv[i];
        }

        float du = sol[0] * wt0 + sol[1] * wt1 + sol[2] * wt2
                 + sol[3] * wt3 + sol[4] * wt4;
        out[row] = sv + dtv * du;

        // rotate pipeline (static indices only)
        if (p < TPL_PTS - 1) {
            #pragma unroll
            for (int q = 0; q < 4; ++q) { ci[q] = ni[q]; cw[q] = nw[q]; }
        }
    }
}

extern "C" void kernel_launch(void* const* d_in, const int* in_sizes, int n_in,
                              void* d_out, int out_size, void* d_ws, size_t ws_size,
                              hipStream_t stream) {
    const float* x          = (const float*)d_in[0];
    const float* points     = (const float*)d_in[1];
    const int*   edge_index = (const int*)d_in[2];
    const float* dtp        = (const float*)d_in[3];
    const float* dist       = (const float*)d_in[4];
    const float* weight     = (const float*)d_in[5];
    float* out = (float*)d_out;

    int total = out_size;                    // B * SIZE = 524288
    int grid  = total / TPL_SPAN;            // 256 blocks (8 per batch)
    size_t lds_bytes = (size_t)TPL_SIZE * sizeof(uint2);  // 128 KB

    tp_lds_kernel<<<grid, TPL_BLK, lds_bytes, stream>>>(
        x, points, edge_index, dtp, dist, weight, out);
}

// Round 11
// 21.040 us; speedup vs baseline: 1.1886x; 1.0050x over previous
//
#include <hip/hip_runtime.h>

#define TPL_SIZE 16384
#define TPL_K 16
#define TPL_ND 5
#define TPL_BLK 512
#define TPL_PTS 4                                  // points per thread
#define TPL_SPAN (TPL_BLK * TPL_PTS)               // 2048 points per block
#define TPL_BPB (TPL_SIZE / TPL_SPAN)              // 8 blocks per batch
#define TPL_NXCD 8

typedef __attribute__((ext_vector_type(2))) float f32x2;

// R10 structure (21.1 us) + packed-fp32 accumulation + coalesced vector staging.
// - 256 blocks x 512 threads; block stages the ENTIRE batch table
//   (16384 x {px_u16|py_u16<<16, v_f32} = 128 KB) into LDS; each thread
//   solves FOUR points with a depth-1 prefetch pipeline on edge/dist.
// - XCD remap: a batch's 8 blocks share blockIdx%8 -> same XCD L2 (R8: -4 us).
// - 512-thread blocks (1024-thread variants hit a 64-VGPR ceiling + spill).
// - rcp-based 5x5 solve (R10: -2.3 us; VALU is on the critical path).
// - NEW (R11): two neighbors per iteration in float2 halves -> monomials and
//   all 20 accumulator FMAs become v_pk_*_f32 (~40% fewer ops in the
//   dominant VALU block). Staging: 16 coalesced iters (float4+float2 loads,
//   uint4 LDS writes) instead of 32 scalar ones (R9's version had a strided
//   load bug; this one is lane-consecutive).
__global__ __launch_bounds__(TPL_BLK, 2) void tp_lds_kernel(
    const float* __restrict__ x,
    const float* __restrict__ points,
    const int*   __restrict__ edge_index,
    const float* __restrict__ dtp,
    const float* __restrict__ dist,
    const float* __restrict__ weight,
    float* __restrict__ out)
{
    extern __shared__ uint2 lds_pv[];   // [TPL_SIZE] = 128 KB

    const int tid = threadIdx.x;
    const int blk = blockIdx.x;

    // blk -> (batch, chunk): xcd = blk&7 ; 4 batches per XCD
    const int xcd   = blk & (TPL_NXCD - 1);
    const int batch = xcd * 4 + (blk >> 6);          // [0,32)
    const int chunk = (blk >> 3) & (TPL_BPB - 1);    // [0,8)

    const size_t base = (size_t)batch * TPL_SIZE + chunk * TPL_SPAN;

    // ---- issue point 0's streaming loads FIRST (latency hides under staging)
    int4   ci[4];
    float4 cw[4];
    {
        const int4*   ei = reinterpret_cast<const int4*>(edge_index + (base + tid) * TPL_K);
        const float4* dw = reinterpret_cast<const float4*>(dist      + (base + tid) * TPL_K);
        ci[0] = ei[0]; ci[1] = ei[1]; ci[2] = ei[2]; ci[3] = ei[3];
        cw[0] = dw[0]; cw[1] = dw[1]; cw[2] = dw[2]; cw[3] = dw[3];
    }

    // ---- stage + quantize the whole batch table into LDS ----
    // 2 entries/thread/iter, fully coalesced: lane tid -> pb4[k*512+tid]
    {
        const float4* pb4 = reinterpret_cast<const float4*>(points + (size_t)batch * TPL_SIZE * 2);
        const float2* xb2 = reinterpret_cast<const float2*>(x + (size_t)batch * TPL_SIZE);
        uint4* lds4 = reinterpret_cast<uint4*>(lds_pv);
        #pragma unroll
        for (int k = 0; k < TPL_SIZE / (2 * TPL_BLK); ++k) {   // 16 iters
            int g = k * TPL_BLK + tid;        // pair-group index
            float4 pp = pb4[g];               // points for entries 2g, 2g+1
            float2 xv = xb2[g];               // values for entries 2g, 2g+1
            unsigned ux0 = (unsigned)(pp.x * 65536.0f);
            unsigned uy0 = (unsigned)(pp.y * 65536.0f);
            unsigned ux1 = (unsigned)(pp.z * 65536.0f);
            unsigned uy1 = (unsigned)(pp.w * 65536.0f);
            if (ux0 > 65535u) ux0 = 65535u;
            if (uy0 > 65535u) uy0 = 65535u;
            if (ux1 > 65535u) ux1 = 65535u;
            if (uy1 > 65535u) uy1 = 65535u;
            uint4 wv;
            wv.x = ux0 | (uy0 << 16);
            wv.y = __float_as_uint(xv.x);
            wv.z = ux1 | (uy1 << 16);
            wv.w = __float_as_uint(xv.y);
            lds4[g] = wv;
        }
    }
    __syncthreads();

    const float wt0 = weight[0], wt1 = weight[1], wt2 = weight[2],
                wt3 = weight[3], wt4 = weight[4];
    const float dtv = dtp[0];

    #pragma unroll
    for (int p = 0; p < TPL_PTS; ++p) {
        // prefetch next point's edge/dist while computing this one
        int4   ni[4];
        float4 nw[4];
        if (p < TPL_PTS - 1) {
            const size_t rown = base + (p + 1) * TPL_BLK + tid;
            const int4*   ei = reinterpret_cast<const int4*>(edge_index + rown * TPL_K);
            const float4* dw = reinterpret_cast<const float4*>(dist      + rown * TPL_K);
            ni[0] = ei[0]; ni[1] = ei[1]; ni[2] = ei[2]; ni[3] = ei[3];
            nw[0] = dw[0]; nw[1] = dw[1]; nw[2] = dw[2]; nw[3] = dw[3];
        }

        const int    s   = chunk * TPL_SPAN + p * TPL_BLK + tid;
        const size_t row = base + p * TPL_BLK + tid;

        // self point from LDS (same quantization as neighbors)
        uint2 se = lds_pv[s];
        unsigned sx = se.x & 0xffffu;
        unsigned sy = se.x >> 16;
        float    sv = __uint_as_float(se.y);

        int ids[TPL_K] = {ci[0].x, ci[0].y, ci[0].z, ci[0].w,
                          ci[1].x, ci[1].y, ci[1].z, ci[1].w,
                          ci[2].x, ci[2].y, ci[2].z, ci[2].w,
                          ci[3].x, ci[3].y, ci[3].z, ci[3].w};
        float wgt[TPL_K] = {cw[0].x, cw[0].y, cw[0].z, cw[0].w,
                            cw[1].x, cw[1].y, cw[1].z, cw[1].w,
                            cw[2].x, cw[2].y, cw[2].z, cw[2].w,
                            cw[3].x, cw[3].y, cw[3].z, cw[3].w};

        uint2 nb[TPL_K];
        #pragma unroll
        for (int t = 0; t < TPL_K; ++t) nb[t] = lds_pv[ids[t] & (TPL_SIZE - 1)];

        // ---- packed accumulation: neighbors 2tt (lo) and 2tt+1 (hi) ----
        f32x2 ata2[15], atb2[TPL_ND];
        #pragma unroll
        for (int i = 0; i < 15; ++i) ata2[i] = (f32x2)0.0f;
        #pragma unroll
        for (int i = 0; i < TPL_ND; ++i) atb2[i] = (f32x2)0.0f;

        #pragma unroll
        for (int tt = 0; tt < TPL_K / 2; ++tt) {
            const int t0 = 2 * tt, t1 = 2 * tt + 1;
            int dxi0 = (int)(nb[t0].x & 0xffffu) - (int)sx;
            int dyi0 = (int)(nb[t0].x >> 16)     - (int)sy;
            int dxi1 = (int)(nb[t1].x & 0xffffu) - (int)sx;
            int dyi1 = (int)(nb[t1].x >> 16)     - (int)sy;
            f32x2 dx = (f32x2){(float)dxi0, (float)dxi1} * 0x1p-16f;
            f32x2 dy = (f32x2){(float)dyi0, (float)dyi1} * 0x1p-16f;
            f32x2 w  = {wgt[t0], wgt[t1]};
            f32x2 nv = {__uint_as_float(nb[t0].y), __uint_as_float(nb[t1].y)};
            f32x2 hw = w * 0.5f;
            f32x2 a[TPL_ND];
            a[0] = dx * w;
            a[1] = dy * w;
            a[2] = dx * dx * hw;
            a[3] = dx * dy * w;
            a[4] = dy * dy * hw;
            f32x2 bwv = (nv - sv) * w;
            int c = 0;
            #pragma unroll
            for (int i = 0; i < TPL_ND; ++i) {
                #pragma unroll
                for (int j = i; j < TPL_ND; ++j) { ata2[c] += a[i] * a[j]; ++c; }
                atb2[i] += a[i] * bwv;
            }
        }

        // horizontal reduce lo+hi
        float ata[15], atb[TPL_ND];
        #pragma unroll
        for (int i = 0; i < 15; ++i) ata[i] = ata2[i].x + ata2[i].y;
        #pragma unroll
        for (int i = 0; i < TPL_ND; ++i) atb[i] = atb2[i].x + atb2[i].y;

        // 5x5 SPD solve, fully unrolled Gaussian elimination (regs only)
        // v_rcp_f32 pivots; reciprocals reused in back-substitution.
        float M[TPL_ND][TPL_ND], r[TPL_ND], pinv[TPL_ND];
        {
            int c = 0;
            #pragma unroll
            for (int i = 0; i < TPL_ND; ++i) {
                #pragma unroll
                for (int j = i; j < TPL_ND; ++j) { M[i][j] = ata[c]; M[j][i] = ata[c]; ++c; }
                r[i] = atb[i];
                M[i][i] += 1e-6f;
            }
        }
        #pragma unroll
        for (int i = 0; i < TPL_ND; ++i) {
            float inv = __builtin_amdgcn_rcpf(M[i][i]);
            pinv[i] = inv;
            #pragma unroll
            for (int j = i + 1; j < TPL_ND; ++j) {
                float f = M[j][i] * inv;
                #pragma unroll
                for (int cc = i + 1; cc < TPL_ND; ++cc) M[j][cc] -= f * M[i][cc];
                r[j] -= f * r[i];
            }
        }
        float sol[TPL_ND];
        #pragma unroll
        for (int i = TPL_ND - 1; i >= 0; --i) {
            float sv2 = r[i];
            #pragma unroll
            for (int cc = i + 1; cc < TPL_ND; ++cc) sv2 -= M[i][cc] * sol[cc];
            sol[i] = sv2 * pinv[i];
        }

        float du = sol[0] * wt0 + sol[1] * wt1 + sol[2] * wt2
                 + sol[3] * wt3 + sol[4] * wt4;
        out[row] = sv + dtv * du;

        // rotate pipeline (static indices only)
        if (p < TPL_PTS - 1) {
            #pragma unroll
            for (int q = 0; q < 4; ++q) { ci[q] = ni[q]; cw[q] = nw[q]; }
        }
    }
}

extern "C" void kernel_launch(void* const* d_in, const int* in_sizes, int n_in,
                              void* d_out, int out_size, void* d_ws, size_t ws_size,
                              hipStream_t stream) {
    const float* x          = (const float*)d_in[0];
    const float* points     = (const float*)d_in[1];
    const int*   edge_index = (const int*)d_in[2];
    const float* dtp        = (const float*)d_in[3];
    const float* dist       = (const float*)d_in[4];
    const float* weight     = (const float*)d_in[5];
    float* out = (float*)d_out;

    int total = out_size;                    // B * SIZE = 524288
    int grid  = total / TPL_SPAN;            // 256 blocks (8 per batch)
    size_t lds_bytes = (size_t)TPL_SIZE * sizeof(uint2);  // 128 KB

    tp_lds_kernel<<<grid, TPL_BLK, lds_bytes, stream>>>(
        x, points, edge_index, dtp, dist, weight, out);
}